// Round 2
// baseline (496.553 us; speedup 1.0000x reference)
//
#include <hip/hip_runtime.h>

typedef unsigned short UST;
typedef __attribute__((ext_vector_type(8))) short short8;
typedef __attribute__((ext_vector_type(4))) float f32x4;

// fp32 -> bf16 round-to-nearest-even
__device__ __forceinline__ UST f2bf(float f) {
  unsigned int u = __float_as_uint(f);
  u += 0x7FFFu + ((u >> 16) & 1u);
  return (UST)(u >> 16);
}

// async global->LDS, 16B per lane. lds dest must be wave-uniform base; HW adds lane*16.
__device__ __forceinline__ void gload16(const void* g, void* l) {
  __builtin_amdgcn_global_load_lds((__attribute__((address_space(1))) void*)(g),
                                   (__attribute__((address_space(3))) void*)(l), 16, 0, 0);
}

// ---------------- prep: fp32 -> bf16 ----------------
__global__ __launch_bounds__(256) void k_cvt_bf16(const float* __restrict__ X,
                                                  UST* __restrict__ Y, int n8) {
  int i = blockIdx.x * 256 + threadIdx.x;
  if (i >= n8) return;
  const float4* p = (const float4*)(X + (size_t)i * 8);
  float4 a = p[0], b = p[1];
  short8 o;
  o[0] = (short)f2bf(a.x); o[1] = (short)f2bf(a.y);
  o[2] = (short)f2bf(a.z); o[3] = (short)f2bf(a.w);
  o[4] = (short)f2bf(b.x); o[5] = (short)f2bf(b.y);
  o[6] = (short)f2bf(b.z); o[7] = (short)f2bf(b.w);
  *(short8*)(Y + (size_t)i * 8) = o;
}

// ---------------- prep: W [K][N] fp32 -> W^T [N][K] bf16 ----------------
__global__ __launch_bounds__(256) void k_transpose_bf16(const float* __restrict__ W,
                                                        UST* __restrict__ WT, int K, int N) {
  __shared__ float tile[64][65];
  int n0 = blockIdx.x * 64, k0 = blockIdx.y * 64;
  int t = threadIdx.x;
#pragma unroll
  for (int p = 0; p < 16; ++p) {
    int e = p * 256 + t;
    tile[e >> 6][e & 63] = W[(size_t)(k0 + (e >> 6)) * N + n0 + (e & 63)];
  }
  __syncthreads();
#pragma unroll
  for (int p = 0; p < 16; ++p) {
    int e = p * 256 + t;
    WT[(size_t)(n0 + (e >> 6)) * K + k0 + (e & 63)] = f2bf(tile[e & 63][e >> 6]);
  }
}

// ---------------- bf16 MFMA GEMM: C[M][N] = A[M][K] * Bt[N][K]^T + bias ----------------
// 128x128 tile, BK=32, 4 waves in 2x2, each wave 64x64 via 4x4 frags of 16x16x32.
// EPI==1: bf16 out (qkv).  EPI==2: fp32 out (final).
template <int EPI>
__global__ __launch_bounds__(256) void k_gemm_bt(const UST* __restrict__ A,
                                                 const UST* __restrict__ Bt,
                                                 const float* __restrict__ bias,
                                                 void* __restrict__ Cout,
                                                 int M, int N, int K) {
  __shared__ __align__(16) UST Alds[128 * 32];
  __shared__ __align__(16) UST Blds[128 * 32];
  const int t = threadIdx.x, lane = t & 63, w = t >> 6;
  const int lr = lane & 15, lg = lane >> 4;
  const int brow = blockIdx.y * 128, bcol = blockIdx.x * 128;
  const int wr = (w >> 1) * 64, wc = (w & 1) * 64;
  f32x4 acc[4][4] = {};

  for (int k0 = 0; k0 < K; k0 += 32) {
#pragma unroll
    for (int j = 0; j < 2; ++j) {
      int c = j * 256 + t;  // chunk id: row = c>>2, kchunk = c&3 (8 elems each)
      gload16(A + (size_t)(brow + (c >> 2)) * K + k0 + (c & 3) * 8,
              &Alds[(j * 256 + w * 64) * 8]);
      gload16(Bt + (size_t)(bcol + (c >> 2)) * K + k0 + (c & 3) * 8,
              &Blds[(j * 256 + w * 64) * 8]);
    }
    __syncthreads();
    short8 af[4], bf[4];
#pragma unroll
    for (int i = 0; i < 4; ++i) {
      // A-frag: row = lane%16, k = (lane/16)*8..+7 ; B^T read mirrors it
      af[i] = *(const short8*)&Alds[(wr + i * 16 + lr) * 32 + lg * 8];
      bf[i] = *(const short8*)&Blds[(wc + i * 16 + lr) * 32 + lg * 8];
    }
#pragma unroll
    for (int mi = 0; mi < 4; ++mi)
#pragma unroll
      for (int ni = 0; ni < 4; ++ni)
        acc[mi][ni] = __builtin_amdgcn_mfma_f32_16x16x32_bf16(af[mi], bf[ni], acc[mi][ni], 0, 0, 0);
    __syncthreads();
  }
  // epilogue: C/D layout col = lane&15, row = (lane>>4)*4 + r
#pragma unroll
  for (int ni = 0; ni < 4; ++ni) {
    int n = bcol + wc + ni * 16 + lr;
    float bv = bias[n];
#pragma unroll
    for (int mi = 0; mi < 4; ++mi) {
#pragma unroll
      for (int r = 0; r < 4; ++r) {
        int m = brow + wr + mi * 16 + lg * 4 + r;
        float v = acc[mi][ni][r] + bv;
        if (EPI == 1) ((UST*)Cout)[(size_t)m * N + n] = f2bf(v);
        else          ((float*)Cout)[(size_t)m * N + n] = v;
      }
    }
  }
}

// ---------------- flash attention ----------------
// qkv [8192][3072] bf16 rows = [q(16h x 64d) | k | v]. One block = (b,h) x 64 q-rows.
// 4 waves x 16 rows each. Online softmax with the reference's additive -1e8 fp32 mask
// semantics (all-masked rows -> exactly uniform weights, matching the fp32 rounding of
// score + (-1e8)).
__global__ __launch_bounds__(256) void k_attn(const UST* __restrict__ qkv,
                                              const int* __restrict__ L,
                                              UST* __restrict__ Ab) {
  const int qt = blockIdx.x, h = blockIdx.y, b = blockIdx.z;
  const int t = threadIdx.x, lane = t & 63, w = t >> 6;
  const int lr = lane & 15, lg = lane >> 4;
  const int lb = L[b];
  const int q0 = qt * 64;
  const UST* Qg = qkv + (size_t)b * 2048 * 3072 + h * 64;
  const UST* Kg = Qg + 1024;
  const UST* Vg = Qg + 2048;
  __shared__ __align__(16) UST Klds[64 * 64];   // [key][d]
  __shared__ __align__(16) UST VT[64 * 64];     // [d][key]
  __shared__ __align__(16) UST Plds[4 * 16 * 64];
  UST* Pw = &Plds[w * 16 * 64];                 // per-wave [16 q][64 key]
  const int qb = q0 + w * 16;

  short8 qf[2];
#pragma unroll
  for (int kk = 0; kk < 2; ++kk)
    qf[kk] = *(const short8*)&Qg[(size_t)(qb + lr) * 3072 + kk * 32 + lg * 8];

  f32x4 o[4] = {};
  float m_run[4], l_run[4];
#pragma unroll
  for (int r = 0; r < 4; ++r) { m_run[r] = -3.0e38f; l_run[r] = 0.f; }

  // rows with q >= lb need ALL keys (uniform softmax); pure-causal blocks stop at qt.
  const int nt = (lb <= q0 + 63) ? 32 : (qt + 1);

  for (int kt = 0; kt < nt; ++kt) {
    const int kb = kt * 64;
    // stage K [64][64] linear via global_load_lds
#pragma unroll
    for (int j = 0; j < 2; ++j) {
      int c = j * 256 + t;
      gload16(Kg + (size_t)(kb + (c >> 3)) * 3072 + (c & 7) * 8,
              &Klds[(j * 256 + w * 64) * 8]);
    }
    // stage V transposed: read 8 d-elems of one key, scatter into VT[d][key]
#pragma unroll
    for (int j = 0; j < 2; ++j) {
      int c = j * 256 + t;
      int key = c & 63, dcc = c >> 6;
      short8 v8 = *(const short8*)&Vg[(size_t)(kb + key) * 3072 + dcc * 8];
#pragma unroll
      for (int jj = 0; jj < 8; ++jj)
        VT[(dcc * 8 + jj) * 64 + key] = (UST)v8[jj];
    }
    __syncthreads();

    // S = Q K^T : A=Q rows, B-frag = Klds row-major (B^T pattern)
    f32x4 s[4];
#pragma unroll
    for (int kf = 0; kf < 4; ++kf) {
      f32x4 sa = {};
#pragma unroll
      for (int kk = 0; kk < 2; ++kk) {
        short8 kfr = *(const short8*)&Klds[(kf * 16 + lr) * 64 + kk * 32 + lg * 8];
        sa = __builtin_amdgcn_mfma_f32_16x16x32_bf16(qf[kk], kfr, sa, 0, 0, 0);
      }
      s[kf] = sa;
    }
    // scale + additive mask with reference fp32 semantics
#pragma unroll
    for (int kf = 0; kf < 4; ++kf) {
      int key = kb + kf * 16 + lr;
#pragma unroll
      for (int r = 0; r < 4; ++r) {
        int qrow = qb + lg * 4 + r;
        float mad = (qrow < lb && key <= qrow) ? 0.0f : -1e8f;
        s[kf][r] = s[kf][r] * 0.125f + mad;
      }
    }
    // online softmax: row = (lg, r); reduce across lr (16 lanes) via shfl_xor 1,2,4,8
    float corr[4];
#pragma unroll
    for (int r = 0; r < 4; ++r) {
      float v = fmaxf(fmaxf(s[0][r], s[1][r]), fmaxf(s[2][r], s[3][r]));
      v = fmaxf(v, __shfl_xor(v, 1));
      v = fmaxf(v, __shfl_xor(v, 2));
      v = fmaxf(v, __shfl_xor(v, 4));
      v = fmaxf(v, __shfl_xor(v, 8));
      float mn = fmaxf(m_run[r], v);
      corr[r] = __expf(m_run[r] - mn);
      m_run[r] = mn;
    }
    float rs[4] = {0.f, 0.f, 0.f, 0.f};
#pragma unroll
    for (int kf = 0; kf < 4; ++kf) {
#pragma unroll
      for (int r = 0; r < 4; ++r) {
        float p = __expf(s[kf][r] - m_run[r]);
        s[kf][r] = p;
        rs[r] += p;
      }
    }
#pragma unroll
    for (int r = 0; r < 4; ++r) {
      float v = rs[r];
      v += __shfl_xor(v, 1);
      v += __shfl_xor(v, 2);
      v += __shfl_xor(v, 4);
      v += __shfl_xor(v, 8);
      l_run[r] = l_run[r] * corr[r] + v;
    }
    // P -> per-wave LDS (accum layout write), re-read as A-frags (contiguous b128)
#pragma unroll
    for (int kf = 0; kf < 4; ++kf)
#pragma unroll
      for (int r = 0; r < 4; ++r)
        Pw[(lg * 4 + r) * 64 + kf * 16 + lr] = f2bf(s[kf][r]);
#pragma unroll
    for (int df = 0; df < 4; ++df)
#pragma unroll
      for (int r = 0; r < 4; ++r)
        o[df][r] *= corr[r];
    // O += P V : A = P (from Pw), B-frag = VT row-major (B^T pattern, n=d, k=key)
#pragma unroll
    for (int kk = 0; kk < 2; ++kk) {
      short8 pf = *(const short8*)&Pw[lr * 64 + kk * 32 + lg * 8];
#pragma unroll
      for (int df = 0; df < 4; ++df) {
        short8 vf = *(const short8*)&VT[(df * 16 + lr) * 64 + kk * 32 + lg * 8];
        o[df] = __builtin_amdgcn_mfma_f32_16x16x32_bf16(pf, vf, o[df], 0, 0, 0);
      }
    }
    __syncthreads();
  }
  // epilogue: Ab[b*2048+q][h*64+d] bf16
#pragma unroll
  for (int df = 0; df < 4; ++df) {
#pragma unroll
    for (int r = 0; r < 4; ++r) {
      int qrow = qb + lg * 4 + r;
      float v = o[df][r] / l_run[r];
      Ab[(size_t)(b * 2048 + qrow) * 1024 + h * 64 + df * 16 + lr] = f2bf(v);
    }
  }
}

extern "C" void kernel_launch(void* const* d_in, const int* in_sizes, int n_in,
                              void* d_out, int out_size, void* d_ws, size_t ws_size,
                              hipStream_t stream) {
  const float* x  = (const float*)d_in[0];
  const int*   l  = (const int*)d_in[1];
  const float* Wa = (const float*)d_in[2];
  const float* ba = (const float*)d_in[3];
  const float* Wp = (const float*)d_in[4];
  const float* bp = (const float*)d_in[5];

  char* ws = (char*)d_ws;
  UST* xb   = (UST*)(ws);                        // [8192][1024] bf16, 16 MB
  UST* WaT  = (UST*)(ws + (16u << 20));          // [3072][1024] bf16, 6 MB
  UST* WpT  = (UST*)(ws + (22u << 20));          // [1024][1024] bf16, 2 MB
  UST* qkvb = (UST*)(ws + (24u << 20));          // [8192][3072] bf16, 48 MB
  UST* Ab   = xb;  // xb dead after gemm1; reuse for attention output (stream-ordered)

  hipLaunchKernelGGL(k_cvt_bf16, dim3(4096), dim3(256), 0, stream, x, xb, 1048576);
  hipLaunchKernelGGL(k_transpose_bf16, dim3(48, 16), dim3(256), 0, stream, Wa, WaT, 1024, 3072);
  hipLaunchKernelGGL(k_transpose_bf16, dim3(16, 16), dim3(256), 0, stream, Wp, WpT, 1024, 1024);
  hipLaunchKernelGGL((k_gemm_bt<1>), dim3(24, 64), dim3(256), 0, stream,
                     xb, WaT, ba, (void*)qkvb, 8192, 3072, 1024);
  hipLaunchKernelGGL(k_attn, dim3(32, 16, 4), dim3(256), 0, stream, qkvb, l, Ab);
  hipLaunchKernelGGL((k_gemm_bt<2>), dim3(8, 64), dim3(256), 0, stream,
                     Ab, WpT, bp, d_out, 8192, 1024, 1024);
}

// Round 5
// 300.314 us; speedup vs baseline: 1.6534x; 1.6534x over previous
//
#include <hip/hip_runtime.h>

typedef unsigned short UST;
typedef __attribute__((ext_vector_type(8))) short short8;
typedef __attribute__((ext_vector_type(4))) float f32x4;

// fp32 -> bf16 round-to-nearest-even
__device__ __forceinline__ UST f2bf(float f) {
  unsigned int u = __float_as_uint(f);
  u += 0x7FFFu + ((u >> 16) & 1u);
  return (UST)(u >> 16);
}
__device__ __forceinline__ float bf2f(UST u) {
  unsigned int x = ((unsigned int)u) << 16;
  return __uint_as_float(x);
}

// async global->LDS, 16B per lane. lds dest must be wave-uniform base; HW adds lane*16.
__device__ __forceinline__ void gload16(const void* g, void* l) {
  __builtin_amdgcn_global_load_lds((__attribute__((address_space(1))) void*)(g),
                                   (__attribute__((address_space(3))) void*)(l), 16, 0, 0);
}

// ---------------- prep: fp32 -> bf16 ----------------
__global__ __launch_bounds__(256) void k_cvt_bf16(const float* __restrict__ X,
                                                  UST* __restrict__ Y, int n8) {
  int i = blockIdx.x * 256 + threadIdx.x;
  if (i >= n8) return;
  const float4* p = (const float4*)(X + (size_t)i * 8);
  float4 a = p[0], b = p[1];
  short8 o;
  o[0] = (short)f2bf(a.x); o[1] = (short)f2bf(a.y);
  o[2] = (short)f2bf(a.z); o[3] = (short)f2bf(a.w);
  o[4] = (short)f2bf(b.x); o[5] = (short)f2bf(b.y);
  o[6] = (short)f2bf(b.z); o[7] = (short)f2bf(b.w);
  *(short8*)(Y + (size_t)i * 8) = o;
}

// ---------------- prep: W [K][N] fp32 -> W^T [N][K] bf16 ----------------
__global__ __launch_bounds__(256) void k_transpose_bf16(const float* __restrict__ W,
                                                        UST* __restrict__ WT, int K, int N) {
  __shared__ float tile[64][65];
  int n0 = blockIdx.x * 64, k0 = blockIdx.y * 64;
  int t = threadIdx.x;
#pragma unroll
  for (int p = 0; p < 16; ++p) {
    int e = p * 256 + t;
    tile[e >> 6][e & 63] = W[(size_t)(k0 + (e >> 6)) * N + n0 + (e & 63)];
  }
  __syncthreads();
#pragma unroll
  for (int p = 0; p < 16; ++p) {
    int e = p * 256 + t;
    WT[(size_t)(n0 + (e >> 6)) * K + k0 + (e & 63)] = f2bf(tile[e & 63][e >> 6]);
  }
}

// ---------------- bf16 MFMA GEMM: C[M][N] = A[M][K] * Bt[N][K]^T + bias ----------------
// 128x128 tile, BK=32, 4 waves in 2x2, each wave 64x64 via 4x4 frags of 16x16x32.
// 1D grid of GX*GY blocks with XCD-aware bijective swizzle (nwg % 8 == 0 for both
// instantiations: 24*64=1536, 8*64=512). EPI==1: bf16 out (qkv). EPI==2: fp32 out.
template <int EPI, int GX, int GY>
__global__ __launch_bounds__(256) void k_gemm_bt(const UST* __restrict__ A,
                                                 const UST* __restrict__ Bt,
                                                 const float* __restrict__ bias,
                                                 void* __restrict__ Cout,
                                                 int M, int N, int K) {
  __shared__ __align__(16) UST Alds[128 * 32];
  __shared__ __align__(16) UST Blds[128 * 32];
  const int t = threadIdx.x, lane = t & 63, w = t >> 6;
  const int lr = lane & 15, lg = lane >> 4;
  // XCD swizzle: XCD x = (f&7) owns contiguous logical tiles [x*cpx, (x+1)*cpx)
  const int f = blockIdx.x;
  const int cpx = (GX * GY) / 8;
  const int swz = (f & 7) * cpx + (f >> 3);
  const int brow = (swz / GX) * 128, bcol = (swz % GX) * 128;
  const int wr = (w >> 1) * 64, wc = (w & 1) * 64;
  f32x4 acc[4][4] = {};

  for (int k0 = 0; k0 < K; k0 += 32) {
#pragma unroll
    for (int j = 0; j < 2; ++j) {
      int c = j * 256 + t;  // chunk id: row = c>>2, kchunk = c&3 (8 elems each)
      gload16(A + (size_t)(brow + (c >> 2)) * K + k0 + (c & 3) * 8,
              &Alds[(j * 256 + w * 64) * 8]);
      gload16(Bt + (size_t)(bcol + (c >> 2)) * K + k0 + (c & 3) * 8,
              &Blds[(j * 256 + w * 64) * 8]);
    }
    __syncthreads();
    short8 af[4], bf[4];
#pragma unroll
    for (int i = 0; i < 4; ++i) {
      // A-frag: row = lane%16, k = (lane/16)*8..+7 ; B^T read mirrors it
      af[i] = *(const short8*)&Alds[(wr + i * 16 + lr) * 32 + lg * 8];
      bf[i] = *(const short8*)&Blds[(wc + i * 16 + lr) * 32 + lg * 8];
    }
#pragma unroll
    for (int mi = 0; mi < 4; ++mi)
#pragma unroll
      for (int ni = 0; ni < 4; ++ni)
        acc[mi][ni] = __builtin_amdgcn_mfma_f32_16x16x32_bf16(af[mi], bf[ni], acc[mi][ni], 0, 0, 0);
    __syncthreads();
  }
  // epilogue: C/D layout col = lane&15, row = (lane>>4)*4 + r
#pragma unroll
  for (int ni = 0; ni < 4; ++ni) {
    int n = bcol + wc + ni * 16 + lr;
    float bv = bias[n];
#pragma unroll
    for (int mi = 0; mi < 4; ++mi) {
#pragma unroll
      for (int r = 0; r < 4; ++r) {
        int m = brow + wr + mi * 16 + lg * 4 + r;
        float v = acc[mi][ni][r] + bv;
        if (EPI == 1) ((UST*)Cout)[(size_t)m * N + n] = f2bf(v);
        else          ((float*)Cout)[(size_t)m * N + n] = v;
      }
    }
  }
}

// ---------------- V partial sums: pbuf[z][b][h][64] = sum over keys z*512..z*512+511 ----------------
__global__ __launch_bounds__(256) void k_vsum(const UST* __restrict__ qkv,
                                              float* __restrict__ pbuf) {
  const int h = blockIdx.x, b = blockIdx.y, z = blockIdx.z;
  const int t = threadIdx.x;
  const int dgrp = t & 7, kslot = t >> 3;  // d = dgrp*8..+7, 32 key slots
  const UST* Vg = qkv + (size_t)b * 2048 * 3072 + h * 64 + 2048;
  float acc[8] = {0.f, 0.f, 0.f, 0.f, 0.f, 0.f, 0.f, 0.f};
#pragma unroll
  for (int i = 0; i < 16; ++i) {
    int k = z * 512 + kslot * 16 + i;
    short8 v8 = *(const short8*)&Vg[(size_t)k * 3072 + dgrp * 8];
#pragma unroll
    for (int j = 0; j < 8; ++j) acc[j] += bf2f((UST)v8[j]);
  }
  __shared__ float red[32 * 68];
#pragma unroll
  for (int j = 0; j < 8; ++j) red[kslot * 68 + dgrp * 8 + j] = acc[j];
  __syncthreads();
  if (t < 64) {
    float s = 0.f;
#pragma unroll
    for (int ks = 0; ks < 32; ++ks) s += red[ks * 68 + t];
    pbuf[((size_t)(z * 4 + b) * 16 + h) * 64 + t] = s;
  }
}

// ---------------- flash attention ----------------
// qkv [8192][3072] bf16 rows = [q(16h x 64d) | k | v]. One block = (b,h) x 64 q-rows.
// Rows with q >= l_b have an all -1e8 additive mask in fp32 => exactly uniform softmax
// => output = mean(V) (precomputed via k_vsum). Blocks fully above l_b exit early;
// mixed blocks override masked rows in the epilogue. Causal rows sweep nt=qt+1 tiles.
// All LDS tiles XOR-swizzled (chunk ^= row&7) to kill 16-way bank conflicts;
// K staged with pre-swizzled global source (global_load_lds writes linearly).
__global__ __launch_bounds__(256) void k_attn(const UST* __restrict__ qkv,
                                              const int* __restrict__ L,
                                              const float* __restrict__ pbuf,
                                              UST* __restrict__ Ab) {
  const int qt = blockIdx.x, h = blockIdx.y, b = blockIdx.z;
  const int t = threadIdx.x, lane = t & 63, w = t >> 6;
  const int lr = lane & 15, lg = lane >> 4;
  const int lb = L[b];
  const int q0 = qt * 64;
  const int qb = q0 + w * 16;

  // mean(V) over all 2048 keys, needed when any row of this block is >= lb
  const bool need_vm = (lb <= q0 + 63);
  float vm[4];
  if (need_vm) {
    const float* pb = pbuf + ((size_t)b * 16 + h) * 64;
#pragma unroll
    for (int df = 0; df < 4; ++df) {
      int d = df * 16 + lr;
      vm[df] = (pb[d] + pb[4096 + d] + pb[8192 + d] + pb[12288 + d]) * (1.0f / 2048.0f);
    }
  }
  if (q0 >= lb) {  // whole block uniform -> write mean(V), no K/V sweep
#pragma unroll
    for (int df = 0; df < 4; ++df) {
      UST ov = f2bf(vm[df]);
#pragma unroll
      for (int r = 0; r < 4; ++r) {
        int qrow = qb + lg * 4 + r;
        Ab[(size_t)(b * 2048 + qrow) * 1024 + h * 64 + df * 16 + lr] = ov;
      }
    }
    return;
  }

  const UST* Qg = qkv + (size_t)b * 2048 * 3072 + h * 64;
  const UST* Kg = Qg + 1024;
  const UST* Vg = Qg + 2048;
  __shared__ __align__(16) UST Klds[64 * 64];   // [key][d], chunk-swizzled
  __shared__ __align__(16) UST VT[64 * 64];     // [d][key], chunk-swizzled
  __shared__ __align__(16) UST Plds[4 * 16 * 64];
  UST* Pw = &Plds[w * 16 * 64];                 // per-wave [16 q][64 key], chunk-swizzled

  short8 qf[2];
#pragma unroll
  for (int kk = 0; kk < 2; ++kk)
    qf[kk] = *(const short8*)&Qg[(size_t)(qb + lr) * 3072 + kk * 32 + lg * 8];

  f32x4 o[4] = {};
  float m_run[4], l_run[4];
#pragma unroll
  for (int r = 0; r < 4; ++r) { m_run[r] = -3.0e38f; l_run[r] = 0.f; }

  const int nt = qt + 1;  // causal rows only; masked rows overridden in epilogue

  for (int kt = 0; kt < nt; ++kt) {
    const int kb = kt * 64;
    // stage K: linear LDS dest, pre-swizzled global source (chunk cc -> cc^(row&7))
#pragma unroll
    for (int j = 0; j < 2; ++j) {
      int c = j * 256 + t;
      int row = c >> 3, cc = c & 7;
      gload16(Kg + (size_t)(kb + row) * 3072 + ((cc ^ (row & 7)) * 8),
              &Klds[(j * 256 + w * 64) * 8]);
    }
    // stage V transposed via regs: VT[d][key] with chunk swizzle (key ^ (d&7)*8)
#pragma unroll
    for (int j = 0; j < 2; ++j) {
      int c = j * 256 + t;
      int key = c & 63, dcc = c >> 6;
      short8 v8 = *(const short8*)&Vg[(size_t)(kb + key) * 3072 + dcc * 8];
#pragma unroll
      for (int jj = 0; jj < 8; ++jj)
        VT[(dcc * 8 + jj) * 64 + (key ^ (jj * 8))] = (UST)v8[jj];
    }
    __syncthreads();

    // S = Q K^T : B-frag rows kf*16+lr, swizzled chunk = (kk*4+lg)^(lr&7)
    f32x4 s[4];
#pragma unroll
    for (int kf = 0; kf < 4; ++kf) {
      f32x4 sa = {};
#pragma unroll
      for (int kk = 0; kk < 2; ++kk) {
        short8 kfr = *(const short8*)&Klds[(kf * 16 + lr) * 64 + (((kk * 4 + lg) ^ (lr & 7)) * 8)];
        sa = __builtin_amdgcn_mfma_f32_16x16x32_bf16(qf[kk], kfr, sa, 0, 0, 0);
      }
      s[kf] = sa;
    }
    // scale + causal mask (reference fp32 -1e8 semantics)
#pragma unroll
    for (int kf = 0; kf < 4; ++kf) {
      int key = kb + kf * 16 + lr;
#pragma unroll
      for (int r = 0; r < 4; ++r) {
        int qrow = qb + lg * 4 + r;
        float mad = (key <= qrow) ? 0.0f : -1e8f;
        s[kf][r] = s[kf][r] * 0.125f + mad;
      }
    }
    // online softmax: row = (lg, r); reduce across lr (16 lanes) via shfl_xor 1,2,4,8
    float corr[4];
#pragma unroll
    for (int r = 0; r < 4; ++r) {
      float v = fmaxf(fmaxf(s[0][r], s[1][r]), fmaxf(s[2][r], s[3][r]));
      v = fmaxf(v, __shfl_xor(v, 1));
      v = fmaxf(v, __shfl_xor(v, 2));
      v = fmaxf(v, __shfl_xor(v, 4));
      v = fmaxf(v, __shfl_xor(v, 8));
      float mn = fmaxf(m_run[r], v);
      corr[r] = __expf(m_run[r] - mn);
      m_run[r] = mn;
    }
    float rs[4] = {0.f, 0.f, 0.f, 0.f};
#pragma unroll
    for (int kf = 0; kf < 4; ++kf) {
#pragma unroll
      for (int r = 0; r < 4; ++r) {
        float p = __expf(s[kf][r] - m_run[r]);
        s[kf][r] = p;
        rs[r] += p;
      }
    }
#pragma unroll
    for (int r = 0; r < 4; ++r) {
      float v = rs[r];
      v += __shfl_xor(v, 1);
      v += __shfl_xor(v, 2);
      v += __shfl_xor(v, 4);
      v += __shfl_xor(v, 8);
      l_run[r] = l_run[r] * corr[r] + v;
    }
    // P -> per-wave LDS (swizzled: col ^ (row&7)*8), re-read as A-frags
#pragma unroll
    for (int kf = 0; kf < 4; ++kf)
#pragma unroll
      for (int r = 0; r < 4; ++r) {
        int row = lg * 4 + r;
        Pw[row * 64 + ((kf * 16 + lr) ^ ((row & 7) * 8))] = f2bf(s[kf][r]);
      }
#pragma unroll
    for (int df = 0; df < 4; ++df)
#pragma unroll
      for (int r = 0; r < 4; ++r)
        o[df][r] *= corr[r];
    // O += P V : A-frag from Pw (row=lr), B-frag from VT (row=df*16+lr), both swizzled
#pragma unroll
    for (int kk = 0; kk < 2; ++kk) {
      short8 pf = *(const short8*)&Pw[lr * 64 + ((kk * 32 + lg * 8) ^ ((lr & 7) * 8))];
#pragma unroll
      for (int df = 0; df < 4; ++df) {
        short8 vf = *(const short8*)&VT[(df * 16 + lr) * 64 + (((kk * 4 + lg) ^ (lr & 7)) * 8)];
        o[df] = __builtin_amdgcn_mfma_f32_16x16x32_bf16(pf, vf, o[df], 0, 0, 0);
      }
    }
    __syncthreads();
  }
  // epilogue: Ab[b*2048+q][h*64+d] bf16; masked rows (q >= lb) get mean(V)
#pragma unroll
  for (int df = 0; df < 4; ++df) {
#pragma unroll
    for (int r = 0; r < 4; ++r) {
      int qrow = qb + lg * 4 + r;
      float v = (qrow >= lb) ? vm[df] : o[df][r] / l_run[r];
      Ab[(size_t)(b * 2048 + qrow) * 1024 + h * 64 + df * 16 + lr] = f2bf(v);
    }
  }
}

extern "C" void kernel_launch(void* const* d_in, const int* in_sizes, int n_in,
                              void* d_out, int out_size, void* d_ws, size_t ws_size,
                              hipStream_t stream) {
  const float* x  = (const float*)d_in[0];
  const int*   l  = (const int*)d_in[1];
  const float* Wa = (const float*)d_in[2];
  const float* ba = (const float*)d_in[3];
  const float* Wp = (const float*)d_in[4];
  const float* bp = (const float*)d_in[5];

  char* ws = (char*)d_ws;
  UST* xb     = (UST*)(ws);                      // [8192][1024] bf16, 16 MB
  UST* WaT    = (UST*)(ws + (16u << 20));        // [3072][1024] bf16, 6 MB
  UST* WpT    = (UST*)(ws + (22u << 20));        // [1024][1024] bf16, 2 MB
  UST* qkvb   = (UST*)(ws + (24u << 20));        // [8192][3072] bf16, 48 MB
  float* pbuf = (float*)(ws + (72u << 20));      // [4][4][16][64] f32, 64 KB
  UST* Ab     = xb;  // xb dead after gemm1; reuse for attention output

  hipLaunchKernelGGL(k_cvt_bf16, dim3(4096), dim3(256), 0, stream, x, xb, 1048576);
  hipLaunchKernelGGL(k_transpose_bf16, dim3(48, 16), dim3(256), 0, stream, Wa, WaT, 1024, 3072);
  hipLaunchKernelGGL(k_transpose_bf16, dim3(16, 16), dim3(256), 0, stream, Wp, WpT, 1024, 1024);
  hipLaunchKernelGGL((k_gemm_bt<1, 24, 64>), dim3(1536), dim3(256), 0, stream,
                     xb, WaT, ba, (void*)qkvb, 8192, 3072, 1024);
  hipLaunchKernelGGL(k_vsum, dim3(16, 4, 4), dim3(256), 0, stream, qkvb, pbuf);
  hipLaunchKernelGGL(k_attn, dim3(32, 16, 4), dim3(256), 0, stream, qkvb, l, pbuf, Ab);
  hipLaunchKernelGGL((k_gemm_bt<2, 8, 64>), dim3(512), dim3(256), 0, stream,
                     Ab, WpT, bp, d_out, 8192, 1024, 1024);
}

// Round 6
// 295.799 us; speedup vs baseline: 1.6787x; 1.0153x over previous
//
#include <hip/hip_runtime.h>

typedef unsigned short UST;
typedef __attribute__((ext_vector_type(8))) short short8;
typedef __attribute__((ext_vector_type(4))) float f32x4;

// fp32 -> bf16 round-to-nearest-even
__device__ __forceinline__ UST f2bf(float f) {
  unsigned int u = __float_as_uint(f);
  u += 0x7FFFu + ((u >> 16) & 1u);
  return (UST)(u >> 16);
}
__device__ __forceinline__ float bf2f(UST u) {
  unsigned int x = ((unsigned int)u) << 16;
  return __uint_as_float(x);
}

// async global->LDS, 16B per lane. lds dest must be wave-uniform base; HW adds lane*16.
__device__ __forceinline__ void gload16(const void* g, void* l) {
  __builtin_amdgcn_global_load_lds((__attribute__((address_space(1))) void*)(g),
                                   (__attribute__((address_space(3))) void*)(l), 16, 0, 0);
}

// ---------------- prep: fp32 -> bf16 ----------------
__global__ __launch_bounds__(256) void k_cvt_bf16(const float* __restrict__ X,
                                                  UST* __restrict__ Y, int n8) {
  int i = blockIdx.x * 256 + threadIdx.x;
  if (i >= n8) return;
  const float4* p = (const float4*)(X + (size_t)i * 8);
  float4 a = p[0], b = p[1];
  short8 o;
  o[0] = (short)f2bf(a.x); o[1] = (short)f2bf(a.y);
  o[2] = (short)f2bf(a.z); o[3] = (short)f2bf(a.w);
  o[4] = (short)f2bf(b.x); o[5] = (short)f2bf(b.y);
  o[6] = (short)f2bf(b.z); o[7] = (short)f2bf(b.w);
  *(short8*)(Y + (size_t)i * 8) = o;
}

// ---------------- prep: W [K][N] fp32 -> W^T [N][K] bf16 ----------------
__global__ __launch_bounds__(256) void k_transpose_bf16(const float* __restrict__ W,
                                                        UST* __restrict__ WT, int K, int N) {
  __shared__ float tile[64][65];
  int n0 = blockIdx.x * 64, k0 = blockIdx.y * 64;
  int t = threadIdx.x;
#pragma unroll
  for (int p = 0; p < 16; ++p) {
    int e = p * 256 + t;
    tile[e >> 6][e & 63] = W[(size_t)(k0 + (e >> 6)) * N + n0 + (e & 63)];
  }
  __syncthreads();
#pragma unroll
  for (int p = 0; p < 16; ++p) {
    int e = p * 256 + t;
    WT[(size_t)(n0 + (e >> 6)) * K + k0 + (e & 63)] = f2bf(tile[e & 63][e >> 6]);
  }
}

// ---------------- bf16 MFMA GEMM: C[M][N] = A[M][K] * Bt[N][K]^T + bias ----------------
// 128x128 tile, BK=32, 4 waves in 2x2, each wave 64x64 via 4x4 frags of 16x16x32.
// 1D grid of GX*GY blocks with XCD-aware bijective swizzle (nwg % 8 == 0 for both
// instantiations: 24*64=1536, 8*64=512). EPI==1: bf16 out (qkv). EPI==2: fp32 out.
template <int EPI, int GX, int GY>
__global__ __launch_bounds__(256) void k_gemm_bt(const UST* __restrict__ A,
                                                 const UST* __restrict__ Bt,
                                                 const float* __restrict__ bias,
                                                 void* __restrict__ Cout,
                                                 int M, int N, int K) {
  __shared__ __align__(16) UST Alds[128 * 32];
  __shared__ __align__(16) UST Blds[128 * 32];
  const int t = threadIdx.x, lane = t & 63, w = t >> 6;
  const int lr = lane & 15, lg = lane >> 4;
  // XCD swizzle: XCD x = (f&7) owns contiguous logical tiles [x*cpx, (x+1)*cpx)
  const int f = blockIdx.x;
  const int cpx = (GX * GY) / 8;
  const int swz = (f & 7) * cpx + (f >> 3);
  const int brow = (swz / GX) * 128, bcol = (swz % GX) * 128;
  const int wr = (w >> 1) * 64, wc = (w & 1) * 64;
  f32x4 acc[4][4] = {};

  for (int k0 = 0; k0 < K; k0 += 32) {
#pragma unroll
    for (int j = 0; j < 2; ++j) {
      int c = j * 256 + t;  // chunk id: row = c>>2, kchunk = c&3 (8 elems each)
      gload16(A + (size_t)(brow + (c >> 2)) * K + k0 + (c & 3) * 8,
              &Alds[(j * 256 + w * 64) * 8]);
      gload16(Bt + (size_t)(bcol + (c >> 2)) * K + k0 + (c & 3) * 8,
              &Blds[(j * 256 + w * 64) * 8]);
    }
    __syncthreads();
    short8 af[4], bf[4];
#pragma unroll
    for (int i = 0; i < 4; ++i) {
      // A-frag: row = lane%16, k = (lane/16)*8..+7 ; B^T read mirrors it
      af[i] = *(const short8*)&Alds[(wr + i * 16 + lr) * 32 + lg * 8];
      bf[i] = *(const short8*)&Blds[(wc + i * 16 + lr) * 32 + lg * 8];
    }
#pragma unroll
    for (int mi = 0; mi < 4; ++mi)
#pragma unroll
      for (int ni = 0; ni < 4; ++ni)
        acc[mi][ni] = __builtin_amdgcn_mfma_f32_16x16x32_bf16(af[mi], bf[ni], acc[mi][ni], 0, 0, 0);
    __syncthreads();
  }
  // epilogue: C/D layout col = lane&15, row = (lane>>4)*4 + r
#pragma unroll
  for (int ni = 0; ni < 4; ++ni) {
    int n = bcol + wc + ni * 16 + lr;
    float bv = bias[n];
#pragma unroll
    for (int mi = 0; mi < 4; ++mi) {
#pragma unroll
      for (int r = 0; r < 4; ++r) {
        int m = brow + wr + mi * 16 + lg * 4 + r;
        float v = acc[mi][ni][r] + bv;
        if (EPI == 1) ((UST*)Cout)[(size_t)m * N + n] = f2bf(v);
        else          ((float*)Cout)[(size_t)m * N + n] = v;
      }
    }
  }
}

// ---------------- V partial sums: pbuf[z][b][h][64] = sum over keys z*512..z*512+511 ----------------
__global__ __launch_bounds__(256) void k_vsum(const UST* __restrict__ qkv,
                                              float* __restrict__ pbuf) {
  const int h = blockIdx.x, b = blockIdx.y, z = blockIdx.z;
  const int t = threadIdx.x;
  const int dgrp = t & 7, kslot = t >> 3;  // d = dgrp*8..+7, 32 key slots
  const UST* Vg = qkv + (size_t)b * 2048 * 3072 + h * 64 + 2048;
  float acc[8] = {0.f, 0.f, 0.f, 0.f, 0.f, 0.f, 0.f, 0.f};
#pragma unroll
  for (int i = 0; i < 16; ++i) {
    int k = z * 512 + kslot * 16 + i;
    short8 v8 = *(const short8*)&Vg[(size_t)k * 3072 + dgrp * 8];
#pragma unroll
    for (int j = 0; j < 8; ++j) acc[j] += bf2f((UST)v8[j]);
  }
  __shared__ float red[32 * 68];
#pragma unroll
  for (int j = 0; j < 8; ++j) red[kslot * 68 + dgrp * 8 + j] = acc[j];
  __syncthreads();
  if (t < 64) {
    float s = 0.f;
#pragma unroll
    for (int ks = 0; ks < 32; ++ks) s += red[ks * 68 + t];
    pbuf[((size_t)(z * 4 + b) * 16 + h) * 64 + t] = s;
  }
}

// ---------------- flash attention ----------------
// qkv [8192][3072] bf16 rows = [q(16h x 64d) | k | v]. One block = (b,h) x 64 q-rows.
// Rows with q >= l_b: fp32 -1e8 mask => exactly uniform softmax => output = mean(V)
// (k_vsum); such blocks exit early, mixed blocks override in the epilogue.
// Round-6: (a) heavy-first dispatch (qt = 31 - blockIdx.x) to fix triangular tail;
// (b) double-buffered K/VT with prefetch issued BEFORE compute so the end-of-iter
// barrier's vmcnt drain completes under QK^T/softmax/PV (T3 2-phase + T14 pattern).
// All LDS tiles XOR-swizzled (chunk ^= row&7); K staged with pre-swizzled global src.
__global__ __launch_bounds__(256) void k_attn(const UST* __restrict__ qkv,
                                              const int* __restrict__ L,
                                              const float* __restrict__ pbuf,
                                              UST* __restrict__ Ab) {
  const int qt = 31 - (int)blockIdx.x;  // heavy blocks (large nt) dispatch first
  const int h = blockIdx.y, b = blockIdx.z;
  const int t = threadIdx.x, lane = t & 63, w = t >> 6;
  const int lr = lane & 15, lg = lane >> 4;
  const int lb = L[b];
  const int q0 = qt * 64;
  const int qb = q0 + w * 16;

  // mean(V) over all 2048 keys, needed when any row of this block is >= lb
  const bool need_vm = (lb <= q0 + 63);
  float vm[4];
  if (need_vm) {
    const float* pb = pbuf + ((size_t)b * 16 + h) * 64;
#pragma unroll
    for (int df = 0; df < 4; ++df) {
      int d = df * 16 + lr;
      vm[df] = (pb[d] + pb[4096 + d] + pb[8192 + d] + pb[12288 + d]) * (1.0f / 2048.0f);
    }
  }
  if (q0 >= lb) {  // whole block uniform -> write mean(V), no K/V sweep
#pragma unroll
    for (int df = 0; df < 4; ++df) {
      UST ov = f2bf(vm[df]);
#pragma unroll
      for (int r = 0; r < 4; ++r) {
        int qrow = qb + lg * 4 + r;
        Ab[(size_t)(b * 2048 + qrow) * 1024 + h * 64 + df * 16 + lr] = ov;
      }
    }
    return;
  }

  const UST* Qg = qkv + (size_t)b * 2048 * 3072 + h * 64;
  const UST* Kg = Qg + 1024;
  const UST* Vg = Qg + 2048;
  __shared__ __align__(16) UST Klds[2][64 * 64];  // [key][d], chunk-swizzled, dbuf
  __shared__ __align__(16) UST VT[2][64 * 64];    // [d][key], chunk-swizzled, dbuf
  __shared__ __align__(16) UST Plds[4 * 16 * 64];
  UST* Pw = &Plds[w * 16 * 64];                   // per-wave [16 q][64 key], swizzled

  short8 qf[2];
#pragma unroll
  for (int kk = 0; kk < 2; ++kk)
    qf[kk] = *(const short8*)&Qg[(size_t)(qb + lr) * 3072 + kk * 32 + lg * 8];

  f32x4 o[4] = {};
  float m_run[4], l_run[4];
#pragma unroll
  for (int r = 0; r < 4; ++r) { m_run[r] = -3.0e38f; l_run[r] = 0.f; }

  const int nt = qt + 1;  // causal rows only; masked rows overridden in epilogue
  short8 vreg[2];         // V staging regs for the in-flight tile

  // --- staging helpers (kb = key base of tile to stage) ---
  auto stageK = [&](int kb, UST* Kb) {
#pragma unroll
    for (int j = 0; j < 2; ++j) {
      int c = j * 256 + t;
      int row = c >> 3, cc = c & 7;
      gload16(Kg + (size_t)(kb + row) * 3072 + ((cc ^ (row & 7)) * 8),
              &Kb[(j * 256 + w * 64) * 8]);
    }
  };
  auto loadV = [&](int kb) {
#pragma unroll
    for (int j = 0; j < 2; ++j) {
      int c = j * 256 + t;
      vreg[j] = *(const short8*)&Vg[(size_t)(kb + (c & 63)) * 3072 + (c >> 6) * 8];
    }
  };
  auto writeVT = [&](UST* Vb) {
#pragma unroll
    for (int j = 0; j < 2; ++j) {
      int c = j * 256 + t;
      int key = c & 63, dcc = c >> 6;
#pragma unroll
      for (int jj = 0; jj < 8; ++jj)
        Vb[(dcc * 8 + jj) * 64 + (key ^ (jj * 8))] = (UST)vreg[j][jj];
    }
  };

  // prologue: stage tile 0 into buffer 0
  stageK(0, Klds[0]);
  loadV(0);
  writeVT(VT[0]);
  __syncthreads();

  for (int kt = 0; kt < nt; ++kt) {
    const int kb = kt * 64;
    const int cur = kt & 1;
    // issue next-tile prefetch BEFORE compute (latency hides under QK^T/softmax/PV)
    if (kt + 1 < nt) {
      stageK(kb + 64, Klds[cur ^ 1]);
      loadV(kb + 64);
    }

    // S = Q K^T : B-frag rows kf*16+lr, swizzled chunk = (kk*4+lg)^(lr&7)
    const UST* Kb = Klds[cur];
    f32x4 s[4];
#pragma unroll
    for (int kf = 0; kf < 4; ++kf) {
      f32x4 sa = {};
#pragma unroll
      for (int kk = 0; kk < 2; ++kk) {
        short8 kfr = *(const short8*)&Kb[(kf * 16 + lr) * 64 + (((kk * 4 + lg) ^ (lr & 7)) * 8)];
        sa = __builtin_amdgcn_mfma_f32_16x16x32_bf16(qf[kk], kfr, sa, 0, 0, 0);
      }
      s[kf] = sa;
    }
    // scale + causal mask (reference fp32 -1e8 semantics)
#pragma unroll
    for (int kf = 0; kf < 4; ++kf) {
      int key = kb + kf * 16 + lr;
#pragma unroll
      for (int r = 0; r < 4; ++r) {
        int qrow = qb + lg * 4 + r;
        float mad = (key <= qrow) ? 0.0f : -1e8f;
        s[kf][r] = s[kf][r] * 0.125f + mad;
      }
    }
    // online softmax: row = (lg, r); reduce across lr (16 lanes) via shfl_xor 1,2,4,8
    float corr[4];
#pragma unroll
    for (int r = 0; r < 4; ++r) {
      float v = fmaxf(fmaxf(s[0][r], s[1][r]), fmaxf(s[2][r], s[3][r]));
      v = fmaxf(v, __shfl_xor(v, 1));
      v = fmaxf(v, __shfl_xor(v, 2));
      v = fmaxf(v, __shfl_xor(v, 4));
      v = fmaxf(v, __shfl_xor(v, 8));
      float mn = fmaxf(m_run[r], v);
      corr[r] = __expf(m_run[r] - mn);
      m_run[r] = mn;
    }
    float rs[4] = {0.f, 0.f, 0.f, 0.f};
#pragma unroll
    for (int kf = 0; kf < 4; ++kf) {
#pragma unroll
      for (int r = 0; r < 4; ++r) {
        float p = __expf(s[kf][r] - m_run[r]);
        s[kf][r] = p;
        rs[r] += p;
      }
    }
#pragma unroll
    for (int r = 0; r < 4; ++r) {
      float v = rs[r];
      v += __shfl_xor(v, 1);
      v += __shfl_xor(v, 2);
      v += __shfl_xor(v, 4);
      v += __shfl_xor(v, 8);
      l_run[r] = l_run[r] * corr[r] + v;
    }
    // P -> per-wave LDS (swizzled: col ^ (row&7)*8), re-read as A-frags
#pragma unroll
    for (int kf = 0; kf < 4; ++kf)
#pragma unroll
      for (int r = 0; r < 4; ++r) {
        int row = lg * 4 + r;
        Pw[row * 64 + ((kf * 16 + lr) ^ ((row & 7) * 8))] = f2bf(s[kf][r]);
      }
#pragma unroll
    for (int df = 0; df < 4; ++df)
#pragma unroll
      for (int r = 0; r < 4; ++r)
        o[df][r] *= corr[r];
    // O += P V : A-frag from Pw (row=lr), B-frag from VT[cur], both swizzled
    const UST* Vb = VT[cur];
#pragma unroll
    for (int kk = 0; kk < 2; ++kk) {
      short8 pf = *(const short8*)&Pw[lr * 64 + ((kk * 32 + lg * 8) ^ ((lr & 7) * 8))];
#pragma unroll
      for (int df = 0; df < 4; ++df) {
        short8 vf = *(const short8*)&Vb[(df * 16 + lr) * 64 + (((kk * 4 + lg) ^ (lr & 7)) * 8)];
        o[df] = __builtin_amdgcn_mfma_f32_16x16x32_bf16(pf, vf, o[df], 0, 0, 0);
      }
    }
    // write next tile's V (distinct buffer; published by the barrier below)
    if (kt + 1 < nt) writeVT(VT[cur ^ 1]);
    __syncthreads();
  }
  // epilogue: Ab[b*2048+q][h*64+d] bf16; masked rows (q >= lb) get mean(V)
#pragma unroll
  for (int df = 0; df < 4; ++df) {
#pragma unroll
    for (int r = 0; r < 4; ++r) {
      int qrow = qb + lg * 4 + r;
      float v = (qrow >= lb) ? vm[df] : o[df][r] / l_run[r];
      Ab[(size_t)(b * 2048 + qrow) * 1024 + h * 64 + df * 16 + lr] = f2bf(v);
    }
  }
}

extern "C" void kernel_launch(void* const* d_in, const int* in_sizes, int n_in,
                              void* d_out, int out_size, void* d_ws, size_t ws_size,
                              hipStream_t stream) {
  const float* x  = (const float*)d_in[0];
  const int*   l  = (const int*)d_in[1];
  const float* Wa = (const float*)d_in[2];
  const float* ba = (const float*)d_in[3];
  const float* Wp = (const float*)d_in[4];
  const float* bp = (const float*)d_in[5];

  char* ws = (char*)d_ws;
  UST* xb     = (UST*)(ws);                      // [8192][1024] bf16, 16 MB
  UST* WaT    = (UST*)(ws + (16u << 20));        // [3072][1024] bf16, 6 MB
  UST* WpT    = (UST*)(ws + (22u << 20));        // [1024][1024] bf16, 2 MB
  UST* qkvb   = (UST*)(ws + (24u << 20));        // [8192][3072] bf16, 48 MB
  float* pbuf = (float*)(ws + (72u << 20));      // [4][4][16][64] f32, 64 KB
  UST* Ab     = xb;  // xb dead after gemm1; reuse for attention output

  hipLaunchKernelGGL(k_cvt_bf16, dim3(4096), dim3(256), 0, stream, x, xb, 1048576);
  hipLaunchKernelGGL(k_transpose_bf16, dim3(48, 16), dim3(256), 0, stream, Wa, WaT, 1024, 3072);
  hipLaunchKernelGGL(k_transpose_bf16, dim3(16, 16), dim3(256), 0, stream, Wp, WpT, 1024, 1024);
  hipLaunchKernelGGL((k_gemm_bt<1, 24, 64>), dim3(1536), dim3(256), 0, stream,
                     xb, WaT, ba, (void*)qkvb, 8192, 3072, 1024);
  hipLaunchKernelGGL(k_vsum, dim3(16, 4, 4), dim3(256), 0, stream, qkvb, pbuf);
  hipLaunchKernelGGL(k_attn, dim3(32, 16, 4), dim3(256), 0, stream, qkvb, l, pbuf, Ab);
  hipLaunchKernelGGL((k_gemm_bt<2, 8, 64>), dim3(512), dim3(256), 0, stream,
                     Ab, WpT, bp, d_out, 8192, 1024, 1024);
}

// Round 8
// 278.885 us; speedup vs baseline: 1.7805x; 1.0606x over previous
//
#include <hip/hip_runtime.h>

typedef unsigned short UST;
typedef __attribute__((ext_vector_type(8))) short short8;
typedef __attribute__((ext_vector_type(4))) float f32x4;

// fp32 -> bf16 round-to-nearest-even
__device__ __forceinline__ UST f2bf(float f) {
  unsigned int u = __float_as_uint(f);
  u += 0x7FFFu + ((u >> 16) & 1u);
  return (UST)(u >> 16);
}
__device__ __forceinline__ float bf2f(UST u) {
  unsigned int x = ((unsigned int)u) << 16;
  return __uint_as_float(x);
}

// async global->LDS, 16B per lane. lds dest must be wave-uniform base; HW adds lane*16.
__device__ __forceinline__ void gload16(const void* g, void* l) {
  __builtin_amdgcn_global_load_lds((__attribute__((address_space(1))) void*)(g),
                                   (__attribute__((address_space(3))) void*)(l), 16, 0, 0);
}

// ---------------- prep: fp32 -> bf16 ----------------
__global__ __launch_bounds__(256) void k_cvt_bf16(const float* __restrict__ X,
                                                  UST* __restrict__ Y, int n8) {
  int i = blockIdx.x * 256 + threadIdx.x;
  if (i >= n8) return;
  const float4* p = (const float4*)(X + (size_t)i * 8);
  float4 a = p[0], b = p[1];
  short8 o;
  o[0] = (short)f2bf(a.x); o[1] = (short)f2bf(a.y);
  o[2] = (short)f2bf(a.z); o[3] = (short)f2bf(a.w);
  o[4] = (short)f2bf(b.x); o[5] = (short)f2bf(b.y);
  o[6] = (short)f2bf(b.z); o[7] = (short)f2bf(b.w);
  *(short8*)(Y + (size_t)i * 8) = o;
}

// ---------------- prep: W [K][N] fp32 -> W^T [N][K] bf16 ----------------
__global__ __launch_bounds__(256) void k_transpose_bf16(const float* __restrict__ W,
                                                        UST* __restrict__ WT, int K, int N) {
  __shared__ float tile[64][65];
  int n0 = blockIdx.x * 64, k0 = blockIdx.y * 64;
  int t = threadIdx.x;
#pragma unroll
  for (int p = 0; p < 16; ++p) {
    int e = p * 256 + t;
    tile[e >> 6][e & 63] = W[(size_t)(k0 + (e >> 6)) * N + n0 + (e & 63)];
  }
  __syncthreads();
#pragma unroll
  for (int p = 0; p < 16; ++p) {
    int e = p * 256 + t;
    WT[(size_t)(n0 + (e >> 6)) * K + k0 + (e & 63)] = f2bf(tile[e & 63][e >> 6]);
  }
}

// ---------------- bf16 MFMA GEMM: C[M][N] = A[M][K] * Bt[N][K]^T + bias ----------------
// 128x128 tile, BK=32, 4 waves in 2x2, each wave 64x64 via 4x4 frags of 16x16x32.
// 1D grid of GX*GY blocks with XCD-aware bijective swizzle (nwg % 8 == 0 for both
// instantiations: 24*64=1536, 8*64=512). EPI==1: bf16 out (qkv). EPI==2: fp32 out.
template <int EPI, int GX, int GY>
__global__ __launch_bounds__(256) void k_gemm_bt(const UST* __restrict__ A,
                                                 const UST* __restrict__ Bt,
                                                 const float* __restrict__ bias,
                                                 void* __restrict__ Cout,
                                                 int M, int N, int K) {
  __shared__ __align__(16) UST Alds[128 * 32];
  __shared__ __align__(16) UST Blds[128 * 32];
  const int t = threadIdx.x, lane = t & 63, w = t >> 6;
  const int lr = lane & 15, lg = lane >> 4;
  // XCD swizzle: XCD x = (f&7) owns contiguous logical tiles [x*cpx, (x+1)*cpx)
  const int f = blockIdx.x;
  const int cpx = (GX * GY) / 8;
  const int swz = (f & 7) * cpx + (f >> 3);
  const int brow = (swz / GX) * 128, bcol = (swz % GX) * 128;
  const int wr = (w >> 1) * 64, wc = (w & 1) * 64;
  f32x4 acc[4][4] = {};

  for (int k0 = 0; k0 < K; k0 += 32) {
#pragma unroll
    for (int j = 0; j < 2; ++j) {
      int c = j * 256 + t;  // chunk id: row = c>>2, kchunk = c&3 (8 elems each)
      gload16(A + (size_t)(brow + (c >> 2)) * K + k0 + (c & 3) * 8,
              &Alds[(j * 256 + w * 64) * 8]);
      gload16(Bt + (size_t)(bcol + (c >> 2)) * K + k0 + (c & 3) * 8,
              &Blds[(j * 256 + w * 64) * 8]);
    }
    __syncthreads();
    short8 af[4], bf[4];
#pragma unroll
    for (int i = 0; i < 4; ++i) {
      // A-frag: row = lane%16, k = (lane/16)*8..+7 ; B^T read mirrors it
      af[i] = *(const short8*)&Alds[(wr + i * 16 + lr) * 32 + lg * 8];
      bf[i] = *(const short8*)&Blds[(wc + i * 16 + lr) * 32 + lg * 8];
    }
#pragma unroll
    for (int mi = 0; mi < 4; ++mi)
#pragma unroll
      for (int ni = 0; ni < 4; ++ni)
        acc[mi][ni] = __builtin_amdgcn_mfma_f32_16x16x32_bf16(af[mi], bf[ni], acc[mi][ni], 0, 0, 0);
    __syncthreads();
  }
  // epilogue: C/D layout col = lane&15, row = (lane>>4)*4 + r
#pragma unroll
  for (int ni = 0; ni < 4; ++ni) {
    int n = bcol + wc + ni * 16 + lr;
    float bv = bias[n];
#pragma unroll
    for (int mi = 0; mi < 4; ++mi) {
#pragma unroll
      for (int r = 0; r < 4; ++r) {
        int m = brow + wr + mi * 16 + lg * 4 + r;
        float v = acc[mi][ni][r] + bv;
        if (EPI == 1) ((UST*)Cout)[(size_t)m * N + n] = f2bf(v);
        else          ((float*)Cout)[(size_t)m * N + n] = v;
      }
    }
  }
}

// ---------------- V partial sums: pbuf[z][b][h][64] = sum over keys z*512..z*512+511 ----------------
__global__ __launch_bounds__(256) void k_vsum(const UST* __restrict__ qkv,
                                              float* __restrict__ pbuf) {
  const int h = blockIdx.x, b = blockIdx.y, z = blockIdx.z;
  const int t = threadIdx.x;
  const int dgrp = t & 7, kslot = t >> 3;  // d = dgrp*8..+7, 32 key slots
  const UST* Vg = qkv + (size_t)b * 2048 * 3072 + h * 64 + 2048;
  float acc[8] = {0.f, 0.f, 0.f, 0.f, 0.f, 0.f, 0.f, 0.f};
#pragma unroll
  for (int i = 0; i < 16; ++i) {
    int k = z * 512 + kslot * 16 + i;
    short8 v8 = *(const short8*)&Vg[(size_t)k * 3072 + dgrp * 8];
#pragma unroll
    for (int j = 0; j < 8; ++j) acc[j] += bf2f((UST)v8[j]);
  }
  __shared__ float red[32 * 68];
#pragma unroll
  for (int j = 0; j < 8; ++j) red[kslot * 68 + dgrp * 8 + j] = acc[j];
  __syncthreads();
  if (t < 64) {
    float s = 0.f;
#pragma unroll
    for (int ks = 0; ks < 32; ++ks) s += red[ks * 68 + t];
    pbuf[((size_t)(z * 4 + b) * 16 + h) * 64 + t] = s;
  }
}

// ---------------- flash attention ----------------
// qkv [8192][3072] bf16 rows = [q(16h x 64d) | k | v]. One block = (b,h) x 64 q-rows.
// Rows with q >= l_b: fp32 -1e8 mask => exactly uniform softmax => output = mean(V)
// (k_vsum); such blocks exit early, mixed blocks override in the epilogue.
// Round-7: SWAPPED QK^T (S^T = mfma(K,Q)) makes the softmax reduction lane-local:
// each lane owns one q-row (q = qb+lr) and 16 S-values; row max/sum = 15 in-lane
// VALU ops + 2-deep shfl butterfly (xor16, xor32). Per-iter cross-lane ops drop
// 32 shfl -> 8 (2 max + 2 sum + 4 corr/l gathers into the PV accumulator's
// (lg,r) q-domain). K/Q/V/P reads are unchanged; only P-write indexing moves.
// All LDS tiles XOR-swizzled; K staged with pre-swizzled global source; K/VT
// double-buffered with prefetch-before-compute; heavy-first dispatch.
__global__ __launch_bounds__(256) void k_attn(const UST* __restrict__ qkv,
                                              const int* __restrict__ L,
                                              const float* __restrict__ pbuf,
                                              UST* __restrict__ Ab) {
  const int qt = 31 - (int)blockIdx.x;  // heavy blocks (large nt) dispatch first
  const int h = blockIdx.y, b = blockIdx.z;
  const int t = threadIdx.x, lane = t & 63, w = t >> 6;
  const int lr = lane & 15, lg = lane >> 4;
  const int lb = L[b];
  const int q0 = qt * 64;
  const int qb = q0 + w * 16;

  // mean(V) over all 2048 keys, needed when any row of this block is >= lb
  const bool need_vm = (lb <= q0 + 63);
  float vm[4];
  if (need_vm) {
    const float* pb = pbuf + ((size_t)b * 16 + h) * 64;
#pragma unroll
    for (int df = 0; df < 4; ++df) {
      int d = df * 16 + lr;
      vm[df] = (pb[d] + pb[4096 + d] + pb[8192 + d] + pb[12288 + d]) * (1.0f / 2048.0f);
    }
  }
  if (q0 >= lb) {  // whole block uniform -> write mean(V), no K/V sweep
#pragma unroll
    for (int df = 0; df < 4; ++df) {
      UST ov = f2bf(vm[df]);
#pragma unroll
      for (int r = 0; r < 4; ++r) {
        int qrow = qb + lg * 4 + r;
        Ab[(size_t)(b * 2048 + qrow) * 1024 + h * 64 + df * 16 + lr] = ov;
      }
    }
    return;
  }

  const UST* Qg = qkv + (size_t)b * 2048 * 3072 + h * 64;
  const UST* Kg = Qg + 1024;
  const UST* Vg = Qg + 2048;
  __shared__ __align__(16) UST Klds[2][64 * 64];  // [key][d], chunk-swizzled, dbuf
  __shared__ __align__(16) UST VT[2][64 * 64];    // [d][key], chunk-swizzled, dbuf
  __shared__ __align__(16) UST Plds[4 * 16 * 64];
  UST* Pw = &Plds[w * 16 * 64];                   // per-wave [16 q][64 key], swizzled

  short8 qf[2];
#pragma unroll
  for (int kk = 0; kk < 2; ++kk)
    qf[kk] = *(const short8*)&Qg[(size_t)(qb + lr) * 3072 + kk * 32 + lg * 8];

  f32x4 o[4] = {};                 // PV acc: d = df*16+lr (col), q = qb+lg*4+r (row)
  float m_run = -3.0e38f, l_run = 0.f;  // softmax state for q = qb+lr (lane-local)
  const int qrow_l = qb + lr;      // this lane's softmax q-row

  const int nt = qt + 1;  // causal rows only; masked rows overridden in epilogue
  short8 vreg[2];         // V staging regs for the in-flight tile

  // --- staging helpers (kb = key base of tile to stage) ---
  auto stageK = [&](int kb, UST* Kb) {
#pragma unroll
    for (int j = 0; j < 2; ++j) {
      int c = j * 256 + t;
      int row = c >> 3, cc = c & 7;
      gload16(Kg + (size_t)(kb + row) * 3072 + ((cc ^ (row & 7)) * 8),
              &Kb[(j * 256 + w * 64) * 8]);
    }
  };
  auto loadV = [&](int kb) {
#pragma unroll
    for (int j = 0; j < 2; ++j) {
      int c = j * 256 + t;
      vreg[j] = *(const short8*)&Vg[(size_t)(kb + (c & 63)) * 3072 + (c >> 6) * 8];
    }
  };
  auto writeVT = [&](UST* Vb) {
#pragma unroll
    for (int j = 0; j < 2; ++j) {
      int c = j * 256 + t;
      int key = c & 63, dcc = c >> 6;
#pragma unroll
      for (int jj = 0; jj < 8; ++jj)
        Vb[(dcc * 8 + jj) * 64 + (key ^ (jj * 8))] = (UST)vreg[j][jj];
    }
  };

  // prologue: stage tile 0 into buffer 0
  stageK(0, Klds[0]);
  loadV(0);
  writeVT(VT[0]);
  __syncthreads();

  for (int kt = 0; kt < nt; ++kt) {
    const int kb = kt * 64;
    const int cur = kt & 1;
    // issue next-tile prefetch BEFORE compute (latency hides under QK^T/softmax/PV)
    if (kt + 1 < nt) {
      stageK(kb + 64, Klds[cur ^ 1]);
      loadV(kb + 64);
    }

    // S^T = K Q^T via mfma(A=K_frag, B=Q_frag):
    //   s[kf][r] = S[key = kb+kf*16+lg*4+r][q = qb+lr]
    const UST* Kb = Klds[cur];
    f32x4 s[4];
#pragma unroll
    for (int kf = 0; kf < 4; ++kf) {
      f32x4 sa = {};
#pragma unroll
      for (int kk = 0; kk < 2; ++kk) {
        short8 kfr = *(const short8*)&Kb[(kf * 16 + lr) * 64 + (((kk * 4 + lg) ^ (lr & 7)) * 8)];
        sa = __builtin_amdgcn_mfma_f32_16x16x32_bf16(kfr, qf[kk], sa, 0, 0, 0);
      }
      s[kf] = sa;
    }
    // scale + causal mask (reference fp32 -1e8 semantics); qrow is lane-constant
#pragma unroll
    for (int kf = 0; kf < 4; ++kf) {
#pragma unroll
      for (int r = 0; r < 4; ++r) {
        int key = kb + kf * 16 + lg * 4 + r;
        float mad = (key <= qrow_l) ? 0.0f : -1e8f;
        s[kf][r] = s[kf][r] * 0.125f + mad;
      }
    }
    // lane-local softmax for q = qrow_l: 16 in-lane values + butterfly over lg
    float pm = s[0][0];
#pragma unroll
    for (int kf = 0; kf < 4; ++kf)
#pragma unroll
      for (int r = 0; r < 4; ++r) pm = fmaxf(pm, s[kf][r]);
    pm = fmaxf(pm, __shfl_xor(pm, 16));
    pm = fmaxf(pm, __shfl_xor(pm, 32));
    const float mn = fmaxf(m_run, pm);
    const float corr = __expf(m_run - mn);
    m_run = mn;
    float rs = 0.f;
#pragma unroll
    for (int kf = 0; kf < 4; ++kf)
#pragma unroll
      for (int r = 0; r < 4; ++r) {
        float p = __expf(s[kf][r] - mn);
        s[kf][r] = p;
        rs += p;
      }
    rs += __shfl_xor(rs, 16);
    rs += __shfl_xor(rs, 32);
    l_run = l_run * corr + rs;
    // P -> per-wave LDS: row = lr (q), col = key ^ ((lr&7)*8)  [chunk-bit involution,
    // matches the unchanged PV read below]
#pragma unroll
    for (int kf = 0; kf < 4; ++kf)
#pragma unroll
      for (int r = 0; r < 4; ++r)
        Pw[lr * 64 + ((kf * 16 + lg * 4 + r) ^ ((lr & 7) * 8))] = f2bf(s[kf][r]);
    // gather corr into the accumulator's q-domain (q = qb+lg*4+r lives in lane lg*4+r)
    float co[4];
#pragma unroll
    for (int r = 0; r < 4; ++r) co[r] = __shfl(corr, lg * 4 + r);
#pragma unroll
    for (int df = 0; df < 4; ++df)
#pragma unroll
      for (int r = 0; r < 4; ++r)
        o[df][r] *= co[r];
    // O += P V : A-frag from Pw (row=lr), B-frag from VT[cur], both swizzled
    const UST* Vb = VT[cur];
#pragma unroll
    for (int kk = 0; kk < 2; ++kk) {
      short8 pf = *(const short8*)&Pw[lr * 64 + ((kk * 32 + lg * 8) ^ ((lr & 7) * 8))];
#pragma unroll
      for (int df = 0; df < 4; ++df) {
        short8 vf = *(const short8*)&Vb[(df * 16 + lr) * 64 + (((kk * 4 + lg) ^ (lr & 7)) * 8)];
        o[df] = __builtin_amdgcn_mfma_f32_16x16x32_bf16(pf, vf, o[df], 0, 0, 0);
      }
    }
    // write next tile's V (distinct buffer; published by the barrier below)
    if (kt + 1 < nt) writeVT(VT[cur ^ 1]);
    __syncthreads();
  }
  // epilogue: gather l into (lg,r) domain, divide, write; masked rows get mean(V)
  float l4[4];
#pragma unroll
  for (int r = 0; r < 4; ++r) l4[r] = __shfl(l_run, lg * 4 + r);
#pragma unroll
  for (int df = 0; df < 4; ++df) {
#pragma unroll
    for (int r = 0; r < 4; ++r) {
      int qrow = qb + lg * 4 + r;
      float v = (qrow >= lb) ? vm[df] : o[df][r] / l4[r];
      Ab[(size_t)(b * 2048 + qrow) * 1024 + h * 64 + df * 16 + lr] = f2bf(v);
    }
  }
}

extern "C" void kernel_launch(void* const* d_in, const int* in_sizes, int n_in,
                              void* d_out, int out_size, void* d_ws, size_t ws_size,
                              hipStream_t stream) {
  const float* x  = (const float*)d_in[0];
  const int*   l  = (const int*)d_in[1];
  const float* Wa = (const float*)d_in[2];
  const float* ba = (const float*)d_in[3];
  const float* Wp = (const float*)d_in[4];
  const float* bp = (const float*)d_in[5];

  char* ws = (char*)d_ws;
  UST* xb     = (UST*)(ws);                      // [8192][1024] bf16, 16 MB
  UST* WaT    = (UST*)(ws + (16u << 20));        // [3072][1024] bf16, 6 MB
  UST* WpT    = (UST*)(ws + (22u << 20));        // [1024][1024] bf16, 2 MB
  UST* qkvb   = (UST*)(ws + (24u << 20));        // [8192][3072] bf16, 48 MB
  float* pbuf = (float*)(ws + (72u << 20));      // [4][4][16][64] f32, 64 KB
  UST* Ab     = xb;  // xb dead after gemm1; reuse for attention output

  hipLaunchKernelGGL(k_cvt_bf16, dim3(4096), dim3(256), 0, stream, x, xb, 1048576);
  hipLaunchKernelGGL(k_transpose_bf16, dim3(48, 16), dim3(256), 0, stream, Wa, WaT, 1024, 3072);
  hipLaunchKernelGGL(k_transpose_bf16, dim3(16, 16), dim3(256), 0, stream, Wp, WpT, 1024, 1024);
  hipLaunchKernelGGL((k_gemm_bt<1, 24, 64>), dim3(1536), dim3(256), 0, stream,
                     xb, WaT, ba, (void*)qkvb, 8192, 3072, 1024);
  hipLaunchKernelGGL(k_vsum, dim3(16, 4, 4), dim3(256), 0, stream, qkvb, pbuf);
  hipLaunchKernelGGL(k_attn, dim3(32, 16, 4), dim3(256), 0, stream, qkvb, l, pbuf, Ab);
  hipLaunchKernelGGL((k_gemm_bt<2, 8, 64>), dim3(512), dim3(256), 0, stream,
                     Ab, WpT, bp, d_out, 8192, 1024, 1024);
}

// Round 11
// 268.783 us; speedup vs baseline: 1.8474x; 1.0376x over previous
//
#include <hip/hip_runtime.h>

typedef unsigned short UST;
typedef __attribute__((ext_vector_type(8))) short short8;
typedef __attribute__((ext_vector_type(4))) float f32x4;

// fp32 -> bf16 round-to-nearest-even
__device__ __forceinline__ UST f2bf(float f) {
  unsigned int u = __float_as_uint(f);
  u += 0x7FFFu + ((u >> 16) & 1u);
  return (UST)(u >> 16);
}
__device__ __forceinline__ float bf2f(UST u) {
  unsigned int x = ((unsigned int)u) << 16;
  return __uint_as_float(x);
}

// async global->LDS, 16B per lane. lds dest must be wave-uniform base; HW adds lane*16.
__device__ __forceinline__ void gload16(const void* g, void* l) {
  __builtin_amdgcn_global_load_lds((__attribute__((address_space(1))) void*)(g),
                                   (__attribute__((address_space(3))) void*)(l), 16, 0, 0);
}

// ---------------- prep: fp32 -> bf16 ----------------
__global__ __launch_bounds__(256) void k_cvt_bf16(const float* __restrict__ X,
                                                  UST* __restrict__ Y, int n8) {
  int i = blockIdx.x * 256 + threadIdx.x;
  if (i >= n8) return;
  const float4* p = (const float4*)(X + (size_t)i * 8);
  float4 a = p[0], b = p[1];
  short8 o;
  o[0] = (short)f2bf(a.x); o[1] = (short)f2bf(a.y);
  o[2] = (short)f2bf(a.z); o[3] = (short)f2bf(a.w);
  o[4] = (short)f2bf(b.x); o[5] = (short)f2bf(b.y);
  o[6] = (short)f2bf(b.z); o[7] = (short)f2bf(b.w);
  *(short8*)(Y + (size_t)i * 8) = o;
}

// ---------------- prep: W [K][N] fp32 -> W^T [N][K] bf16 ----------------
__global__ __launch_bounds__(256) void k_transpose_bf16(const float* __restrict__ W,
                                                        UST* __restrict__ WT, int K, int N) {
  __shared__ float tile[64][65];
  int n0 = blockIdx.x * 64, k0 = blockIdx.y * 64;
  int t = threadIdx.x;
#pragma unroll
  for (int p = 0; p < 16; ++p) {
    int e = p * 256 + t;
    tile[e >> 6][e & 63] = W[(size_t)(k0 + (e >> 6)) * N + n0 + (e & 63)];
  }
  __syncthreads();
#pragma unroll
  for (int p = 0; p < 16; ++p) {
    int e = p * 256 + t;
    WT[(size_t)(n0 + (e >> 6)) * K + k0 + (e & 63)] = f2bf(tile[e & 63][e >> 6]);
  }
}

// ---------------- bf16 MFMA GEMM: C[M][N] = A[M][K] * Bt[N][K]^T + bias ----------------
// 128x128 tile, BK=64 (128B LDS rows), 4 waves in 2x2, each wave 64x64 via 4x4 frags
// of 16x16x32 (two kk sub-steps per K-tile). LDS chunk-XOR-swizzled (chunk ^= row&7)
// via pre-swizzled global source (global_load_lds writes linearly) + swizzled b128
// frag reads -> bank-conflict-free at the b128 floor (same involution as k_attn's K
// tile, measured 0 conflicts). 1D grid with XCD-aware bijective swizzle (nwg%8==0:
// 1536 / 512). EPI==1: bf16 out (qkv). EPI==2: fp32 out (final).
template <int EPI, int GX, int GY>
__global__ __launch_bounds__(256) void k_gemm_bt(const UST* __restrict__ A,
                                                 const UST* __restrict__ Bt,
                                                 const float* __restrict__ bias,
                                                 void* __restrict__ Cout,
                                                 int M, int N, int K) {
  __shared__ __align__(16) UST Alds[128 * 64];
  __shared__ __align__(16) UST Blds[128 * 64];
  const int t = threadIdx.x, lane = t & 63, w = t >> 6;
  const int lr = lane & 15, lg = lane >> 4;
  // XCD swizzle: XCD x = (f&7) owns contiguous logical tiles [x*cpx, (x+1)*cpx)
  const int f = blockIdx.x;
  const int cpx = (GX * GY) / 8;
  const int swz = (f & 7) * cpx + (f >> 3);
  const int brow = (swz / GX) * 128, bcol = (swz % GX) * 128;
  const int wr = (w >> 1) * 64, wc = (w & 1) * 64;
  f32x4 acc[4][4] = {};

  for (int k0 = 0; k0 < K; k0 += 64) {
    // stage A,B tiles [128][64]: linear LDS dest, pre-swizzled global chunk cc^(row&7)
#pragma unroll
    for (int j = 0; j < 4; ++j) {
      int c = j * 256 + t;  // chunk id: row = c>>3, cc = c&7 (8 elems each)
      int row = c >> 3, cc = c & 7;
      gload16(A + (size_t)(brow + row) * K + k0 + ((cc ^ (row & 7)) * 8),
              &Alds[(j * 256 + w * 64) * 8]);
      gload16(Bt + (size_t)(bcol + row) * K + k0 + ((cc ^ (row & 7)) * 8),
              &Blds[(j * 256 + w * 64) * 8]);
    }
    __syncthreads();
#pragma unroll
    for (int kk = 0; kk < 2; ++kk) {
      short8 af[4], bf[4];
#pragma unroll
      for (int i = 0; i < 4; ++i) {
        // frag row = *r + i*16 + lr, k-chunk = kk*4+lg, swizzled by ^(lr&7)
        af[i] = *(const short8*)&Alds[(wr + i * 16 + lr) * 64 + (((kk * 4 + lg) ^ (lr & 7)) * 8)];
        bf[i] = *(const short8*)&Blds[(wc + i * 16 + lr) * 64 + (((kk * 4 + lg) ^ (lr & 7)) * 8)];
      }
#pragma unroll
      for (int mi = 0; mi < 4; ++mi)
#pragma unroll
        for (int ni = 0; ni < 4; ++ni)
          acc[mi][ni] = __builtin_amdgcn_mfma_f32_16x16x32_bf16(af[mi], bf[ni], acc[mi][ni], 0, 0, 0);
    }
    __syncthreads();
  }
  // epilogue: C/D layout col = lane&15, row = (lane>>4)*4 + r
#pragma unroll
  for (int ni = 0; ni < 4; ++ni) {
    int n = bcol + wc + ni * 16 + lr;
    float bv = bias[n];
#pragma unroll
    for (int mi = 0; mi < 4; ++mi) {
#pragma unroll
      for (int r = 0; r < 4; ++r) {
        int m = brow + wr + mi * 16 + lg * 4 + r;
        float v = acc[mi][ni][r] + bv;
        if (EPI == 1) ((UST*)Cout)[(size_t)m * N + n] = f2bf(v);
        else          ((float*)Cout)[(size_t)m * N + n] = v;
      }
    }
  }
}

// ---------------- V partial sums: pbuf[z][b][h][64] = sum over keys z*512..z*512+511 ----------------
__global__ __launch_bounds__(256) void k_vsum(const UST* __restrict__ qkv,
                                              float* __restrict__ pbuf) {
  const int h = blockIdx.x, b = blockIdx.y, z = blockIdx.z;
  const int t = threadIdx.x;
  const int dgrp = t & 7, kslot = t >> 3;  // d = dgrp*8..+7, 32 key slots
  const UST* Vg = qkv + (size_t)b * 2048 * 3072 + h * 64 + 2048;
  float acc[8] = {0.f, 0.f, 0.f, 0.f, 0.f, 0.f, 0.f, 0.f};
#pragma unroll
  for (int i = 0; i < 16; ++i) {
    int k = z * 512 + kslot * 16 + i;
    short8 v8 = *(const short8*)&Vg[(size_t)k * 3072 + dgrp * 8];
#pragma unroll
    for (int j = 0; j < 8; ++j) acc[j] += bf2f((UST)v8[j]);
  }
  __shared__ float red[32 * 68];
#pragma unroll
  for (int j = 0; j < 8; ++j) red[kslot * 68 + dgrp * 8 + j] = acc[j];
  __syncthreads();
  if (t < 64) {
    float s = 0.f;
#pragma unroll
    for (int ks = 0; ks < 32; ++ks) s += red[ks * 68 + t];
    pbuf[((size_t)(z * 4 + b) * 16 + h) * 64 + t] = s;
  }
}

// ---------------- flash attention (frozen from Round 7) ----------------
// Swapped QK^T (S^T = mfma(K,Q)) => lane-local softmax; mean(V) shortcut for
// q >= l_b rows; all LDS tiles XOR-swizzled; K/VT double-buffered with
// prefetch-before-compute; heavy-first dispatch.
__global__ __launch_bounds__(256) void k_attn(const UST* __restrict__ qkv,
                                              const int* __restrict__ L,
                                              const float* __restrict__ pbuf,
                                              UST* __restrict__ Ab) {
  const int qt = 31 - (int)blockIdx.x;  // heavy blocks (large nt) dispatch first
  const int h = blockIdx.y, b = blockIdx.z;
  const int t = threadIdx.x, lane = t & 63, w = t >> 6;
  const int lr = lane & 15, lg = lane >> 4;
  const int lb = L[b];
  const int q0 = qt * 64;
  const int qb = q0 + w * 16;

  // mean(V) over all 2048 keys, needed when any row of this block is >= lb
  const bool need_vm = (lb <= q0 + 63);
  float vm[4];
  if (need_vm) {
    const float* pb = pbuf + ((size_t)b * 16 + h) * 64;
#pragma unroll
    for (int df = 0; df < 4; ++df) {
      int d = df * 16 + lr;
      vm[df] = (pb[d] + pb[4096 + d] + pb[8192 + d] + pb[12288 + d]) * (1.0f / 2048.0f);
    }
  }
  if (q0 >= lb) {  // whole block uniform -> write mean(V), no K/V sweep
#pragma unroll
    for (int df = 0; df < 4; ++df) {
      UST ov = f2bf(vm[df]);
#pragma unroll
      for (int r = 0; r < 4; ++r) {
        int qrow = qb + lg * 4 + r;
        Ab[(size_t)(b * 2048 + qrow) * 1024 + h * 64 + df * 16 + lr] = ov;
      }
    }
    return;
  }

  const UST* Qg = qkv + (size_t)b * 2048 * 3072 + h * 64;
  const UST* Kg = Qg + 1024;
  const UST* Vg = Qg + 2048;
  __shared__ __align__(16) UST Klds[2][64 * 64];  // [key][d], chunk-swizzled, dbuf
  __shared__ __align__(16) UST VT[2][64 * 64];    // [d][key], chunk-swizzled, dbuf
  __shared__ __align__(16) UST Plds[4 * 16 * 64];
  UST* Pw = &Plds[w * 16 * 64];                   // per-wave [16 q][64 key], swizzled

  short8 qf[2];
#pragma unroll
  for (int kk = 0; kk < 2; ++kk)
    qf[kk] = *(const short8*)&Qg[(size_t)(qb + lr) * 3072 + kk * 32 + lg * 8];

  f32x4 o[4] = {};                 // PV acc: d = df*16+lr (col), q = qb+lg*4+r (row)
  float m_run = -3.0e38f, l_run = 0.f;  // softmax state for q = qb+lr (lane-local)
  const int qrow_l = qb + lr;      // this lane's softmax q-row

  const int nt = qt + 1;  // causal rows only; masked rows overridden in epilogue
  short8 vreg[2];         // V staging regs for the in-flight tile

  // --- staging helpers (kb = key base of tile to stage) ---
  auto stageK = [&](int kb, UST* Kb) {
#pragma unroll
    for (int j = 0; j < 2; ++j) {
      int c = j * 256 + t;
      int row = c >> 3, cc = c & 7;
      gload16(Kg + (size_t)(kb + row) * 3072 + ((cc ^ (row & 7)) * 8),
              &Kb[(j * 256 + w * 64) * 8]);
    }
  };
  auto loadV = [&](int kb) {
#pragma unroll
    for (int j = 0; j < 2; ++j) {
      int c = j * 256 + t;
      vreg[j] = *(const short8*)&Vg[(size_t)(kb + (c & 63)) * 3072 + (c >> 6) * 8];
    }
  };
  auto writeVT = [&](UST* Vb) {
#pragma unroll
    for (int j = 0; j < 2; ++j) {
      int c = j * 256 + t;
      int key = c & 63, dcc = c >> 6;
#pragma unroll
      for (int jj = 0; jj < 8; ++jj)
        Vb[(dcc * 8 + jj) * 64 + (key ^ (jj * 8))] = (UST)vreg[j][jj];
    }
  };

  // prologue: stage tile 0 into buffer 0
  stageK(0, Klds[0]);
  loadV(0);
  writeVT(VT[0]);
  __syncthreads();

  for (int kt = 0; kt < nt; ++kt) {
    const int kb = kt * 64;
    const int cur = kt & 1;
    // issue next-tile prefetch BEFORE compute (latency hides under QK^T/softmax/PV)
    if (kt + 1 < nt) {
      stageK(kb + 64, Klds[cur ^ 1]);
      loadV(kb + 64);
    }

    // S^T = K Q^T via mfma(A=K_frag, B=Q_frag):
    //   s[kf][r] = S[key = kb+kf*16+lg*4+r][q = qb+lr]
    const UST* Kb = Klds[cur];
    f32x4 s[4];
#pragma unroll
    for (int kf = 0; kf < 4; ++kf) {
      f32x4 sa = {};
#pragma unroll
      for (int kk = 0; kk < 2; ++kk) {
        short8 kfr = *(const short8*)&Kb[(kf * 16 + lr) * 64 + (((kk * 4 + lg) ^ (lr & 7)) * 8)];
        sa = __builtin_amdgcn_mfma_f32_16x16x32_bf16(kfr, qf[kk], sa, 0, 0, 0);
      }
      s[kf] = sa;
    }
    // scale + causal mask (reference fp32 -1e8 semantics); qrow is lane-constant
#pragma unroll
    for (int kf = 0; kf < 4; ++kf) {
#pragma unroll
      for (int r = 0; r < 4; ++r) {
        int key = kb + kf * 16 + lg * 4 + r;
        float mad = (key <= qrow_l) ? 0.0f : -1e8f;
        s[kf][r] = s[kf][r] * 0.125f + mad;
      }
    }
    // lane-local softmax for q = qrow_l: 16 in-lane values + butterfly over lg
    float pm = s[0][0];
#pragma unroll
    for (int kf = 0; kf < 4; ++kf)
#pragma unroll
      for (int r = 0; r < 4; ++r) pm = fmaxf(pm, s[kf][r]);
    pm = fmaxf(pm, __shfl_xor(pm, 16));
    pm = fmaxf(pm, __shfl_xor(pm, 32));
    const float mn = fmaxf(m_run, pm);
    const float corr = __expf(m_run - mn);
    m_run = mn;
    float rs = 0.f;
#pragma unroll
    for (int kf = 0; kf < 4; ++kf)
#pragma unroll
      for (int r = 0; r < 4; ++r) {
        float p = __expf(s[kf][r] - mn);
        s[kf][r] = p;
        rs += p;
      }
    rs += __shfl_xor(rs, 16);
    rs += __shfl_xor(rs, 32);
    l_run = l_run * corr + rs;
    // P -> per-wave LDS: row = lr (q), col = key ^ ((lr&7)*8)  [chunk-bit involution,
    // matches the unchanged PV read below]
#pragma unroll
    for (int kf = 0; kf < 4; ++kf)
#pragma unroll
      for (int r = 0; r < 4; ++r)
        Pw[lr * 64 + ((kf * 16 + lg * 4 + r) ^ ((lr & 7) * 8))] = f2bf(s[kf][r]);
    // gather corr into the accumulator's q-domain (q = qb+lg*4+r lives in lane lg*4+r)
    float co[4];
#pragma unroll
    for (int r = 0; r < 4; ++r) co[r] = __shfl(corr, lg * 4 + r);
#pragma unroll
    for (int df = 0; df < 4; ++df)
#pragma unroll
      for (int r = 0; r < 4; ++r)
        o[df][r] *= co[r];
    // O += P V : A-frag from Pw (row=lr), B-frag from VT[cur], both swizzled
    const UST* Vb = VT[cur];
#pragma unroll
    for (int kk = 0; kk < 2; ++kk) {
      short8 pf = *(const short8*)&Pw[lr * 64 + ((kk * 32 + lg * 8) ^ ((lr & 7) * 8))];
#pragma unroll
      for (int df = 0; df < 4; ++df) {
        short8 vf = *(const short8*)&Vb[(df * 16 + lr) * 64 + (((kk * 4 + lg) ^ (lr & 7)) * 8)];
        o[df] = __builtin_amdgcn_mfma_f32_16x16x32_bf16(pf, vf, o[df], 0, 0, 0);
      }
    }
    // write next tile's V (distinct buffer; published by the barrier below)
    if (kt + 1 < nt) writeVT(VT[cur ^ 1]);
    __syncthreads();
  }
  // epilogue: gather l into (lg,r) domain, divide, write; masked rows get mean(V)
  float l4[4];
#pragma unroll
  for (int r = 0; r < 4; ++r) l4[r] = __shfl(l_run, lg * 4 + r);
#pragma unroll
  for (int df = 0; df < 4; ++df) {
#pragma unroll
    for (int r = 0; r < 4; ++r) {
      int qrow = qb + lg * 4 + r;
      float v = (qrow >= lb) ? vm[df] : o[df][r] / l4[r];
      Ab[(size_t)(b * 2048 + qrow) * 1024 + h * 64 + df * 16 + lr] = f2bf(v);
    }
  }
}

extern "C" void kernel_launch(void* const* d_in, const int* in_sizes, int n_in,
                              void* d_out, int out_size, void* d_ws, size_t ws_size,
                              hipStream_t stream) {
  const float* x  = (const float*)d_in[0];
  const int*   l  = (const int*)d_in[1];
  const float* Wa = (const float*)d_in[2];
  const float* ba = (const float*)d_in[3];
  const float* Wp = (const float*)d_in[4];
  const float* bp = (const float*)d_in[5];

  char* ws = (char*)d_ws;
  UST* xb     = (UST*)(ws);                      // [8192][1024] bf16, 16 MB
  UST* WaT    = (UST*)(ws + (16u << 20));        // [3072][1024] bf16, 6 MB
  UST* WpT    = (UST*)(ws + (22u << 20));        // [1024][1024] bf16, 2 MB
  UST* qkvb   = (UST*)(ws + (24u << 20));        // [8192][3072] bf16, 48 MB
  float* pbuf = (float*)(ws + (72u << 20));      // [4][4][16][64] f32, 64 KB
  UST* Ab     = xb;  // xb dead after gemm1; reuse for attention output

  hipLaunchKernelGGL(k_cvt_bf16, dim3(4096), dim3(256), 0, stream, x, xb, 1048576);
  hipLaunchKernelGGL(k_transpose_bf16, dim3(48, 16), dim3(256), 0, stream, Wa, WaT, 1024, 3072);
  hipLaunchKernelGGL(k_transpose_bf16, dim3(16, 16), dim3(256), 0, stream, Wp, WpT, 1024, 1024);
  hipLaunchKernelGGL((k_gemm_bt<1, 24, 64>), dim3(1536), dim3(256), 0, stream,
                     xb, WaT, ba, (void*)qkvb, 8192, 3072, 1024);
  hipLaunchKernelGGL(k_vsum, dim3(16, 4, 4), dim3(256), 0, stream, qkvb, pbuf);
  hipLaunchKernelGGL(k_attn, dim3(32, 16, 4), dim3(256), 0, stream, qkvb, l, pbuf, Ab);
  hipLaunchKernelGGL((k_gemm_bt<2, 8, 64>), dim3(512), dim3(256), 0, stream,
                     Ab, WpT, bp, d_out, 8192, 1024, 1024);
}